// Round 16
// baseline (126.388 us; speedup 1.0000x reference)
//
#include <hip/hip_runtime.h>
#include <hip/hip_bf16.h>

// Problem constants
#define B_  8
#define N_  512
#define C_  1024
#define H_  16
#define HD_ 64
#define M_  4096   // B*N

typedef float  f32x4  __attribute__((ext_vector_type(4)));
typedef __bf16 bf16x8 __attribute__((ext_vector_type(8)));
typedef unsigned short ushort_t;

__device__ __forceinline__ ushort_t f2bf(float f) {
  union { float f; unsigned int u; } un; un.f = f;
  unsigned int u = un.u;
  return (ushort_t)((u + 0x7fffu + ((u >> 16) & 1u)) >> 16);  // RNE
}

// async global->LDS, 16B per lane; lds pointer must be wave-uniform (lane*16 added by HW)
__device__ __forceinline__ void gload16(const void* g, void* l) {
  __builtin_amdgcn_global_load_lds((const __attribute__((address_space(1))) void*)g,
                                   (__attribute__((address_space(3))) void*)l, 16, 0, 0);
}
#define SBAR()  __builtin_amdgcn_s_barrier()
#define SCHED() __builtin_amdgcn_sched_barrier(0)
#define VMCNT4() asm volatile("s_waitcnt vmcnt(4)" ::: "memory")
#define VMCNT0() asm volatile("s_waitcnt vmcnt(0)" ::: "memory")
#define LGKM0()  asm volatile("s_waitcnt lgkmcnt(0)" ::: "memory")

// Packed GEMM-operand layout (verified R8/R9):
//   PACK(row,k) = (((row>>7)*32 + (k>>5))*4 + ((k>>3)&3))*1024 + (row&127)*8 + (k&7)
// [mtile][kt][chunk4][row128][8] — the exact linear order gemm staging consumes.

// ---------------------------------------------------------------------------
// Kernel 1: tile-packed prep. Block = one [128r x 32k] tile. (verified R9)
// ---------------------------------------------------------------------------
__global__ __launch_bounds__(256) void prep_pack_kernel(
    const float* __restrict__ x, const float* __restrict__ mu,
    const float* __restrict__ logvar,
    const float* __restrict__ wq, const float* __restrict__ wk,
    const float* __restrict__ wv, const float* __restrict__ wp,
    ushort_t* __restrict__ xb, ushort_t* __restrict__ kp, ushort_t* __restrict__ vp,
    ushort_t* __restrict__ wb, float* __restrict__ l2part) {
  const int bid = blockIdx.x, t = threadIdx.x;
  const int row = t >> 1, cg = (t & 1) * 16;   // row 0..127, k-group 0 or 16
  const int c0 = cg >> 3;                      // chunk base: 0 or 2

  if (bid < 1024) {
    const int mt = bid >> 5, kt = bid & 31;
    const size_t src = (size_t)(mt * 128 + row) * 1024 + kt * 32 + cg;
    ushort_t tx[16] __attribute__((aligned(16)));
    ushort_t tk[16] __attribute__((aligned(16)));
    ushort_t tv[16] __attribute__((aligned(16)));
    float l2 = 0.f;
#pragma unroll
    for (int j = 0; j < 4; ++j) {
      float4 xv = *(const float4*)(x + src + j * 4);
      float4 mv = *(const float4*)(mu + src + j * 4);
      float4 lv = *(const float4*)(logvar + src + j * 4);
      float xa[4] = {xv.x, xv.y, xv.z, xv.w};
      float ma[4] = {mv.x, mv.y, mv.z, mv.w};
      float la[4] = {lv.x, lv.y, lv.z, lv.w};
#pragma unroll
      for (int i = 0; i < 4; ++i) {
        int e = j * 4 + i;
        float bv  = __expf(la[i]) + 8.0f;   // exp(logvar) + sqrt(HD)
        float inv = 1.0f / bv;
        float kf  = ma[i] * inv;
        l2 += ma[i] * kf;                   // mu^2 / bv
        tx[e] = f2bf(xa[i]); tk[e] = f2bf(kf); tv[e] = f2bf(8.0f * kf);
      }
    }
    const size_t tb = (size_t)((mt * 32 + kt) * 4) * 1024 + row * 8;
    *(bf16x8*)(xb + tb + c0 * 1024)       = *(const bf16x8*)(tx);
    *(bf16x8*)(xb + tb + (c0 + 1) * 1024) = *(const bf16x8*)(tx + 8);
    *(bf16x8*)(kp + tb + c0 * 1024)       = *(const bf16x8*)(tk);
    *(bf16x8*)(kp + tb + (c0 + 1) * 1024) = *(const bf16x8*)(tk + 8);
    *(bf16x8*)(vp + tb + c0 * 1024)       = *(const bf16x8*)(tv);
    *(bf16x8*)(vp + tb + (c0 + 1) * 1024) = *(const bf16x8*)(tv + 8);
    l2 += __shfl_xor(l2, 1);               // pair holds full 32-k partial
    if ((t & 1) == 0) l2part[(size_t)(mt * 128 + row) * 32 + kt] = l2;
  } else {
    const int idx = bid - 1024;
    const int sel = idx >> 8, nt = (idx >> 5) & 7, kt = idx & 31;
    const float* src = sel == 0 ? wq : sel == 1 ? wk : sel == 2 ? wv : wp;
    const size_t so = (size_t)(nt * 128 + row) * 1024 + kt * 32 + cg;
    ushort_t tw[16] __attribute__((aligned(16)));
#pragma unroll
    for (int j = 0; j < 4; ++j) {
      float4 v = *(const float4*)(src + so + j * 4);
      tw[j * 4 + 0] = f2bf(v.x); tw[j * 4 + 1] = f2bf(v.y);
      tw[j * 4 + 2] = f2bf(v.z); tw[j * 4 + 3] = f2bf(v.w);
    }
    ushort_t* dst = wb + (size_t)sel * 1048576;
    const size_t tb = (size_t)((nt * 32 + kt) * 4) * 1024 + row * 8;
    *(bf16x8*)(dst + tb + c0 * 1024)       = *(const bf16x8*)(tw);
    *(bf16x8*)(dst + tb + (c0 + 1) * 1024) = *(const bf16x8*)(tw + 8);
  }
}

// ---------------------------------------------------------------------------
// GEMM core, 128x128 tile, BK=32, 256 thr, RING-3 LDS (48KB, 3 blocks/CU).
// PACKED operands: staging is 2 fully-contiguous 8KB runs per tile.
// ---------------------------------------------------------------------------
__device__ __forceinline__ void gemm_tile_r3(const ushort_t* __restrict__ Ag,
                                             const ushort_t* __restrict__ Wg,
                                             int amt, int ant, f32x4 acc[4][4],
                                             ushort_t* lds) {
  const int t = threadIdx.x;
  const int w = t >> 6, lane = t & 63;
  const int wm = w >> 1, wn = w & 1;
  const int chunk = lane >> 4, r15 = lane & 15;
  const int s0 = t, s1 = t + 256;

#define RSTAGE(kt, buf)                                                           \
  do {                                                                            \
    const ushort_t* sa = Ag + (size_t)(amt * 32 + (kt)) * 4096;                   \
    const ushort_t* sb = Wg + (size_t)(ant * 32 + (kt)) * 4096;                   \
    gload16(sa + s0 * 8, lds + (buf) * 4096 + (s0 & ~63) * 8);                    \
    gload16(sa + s1 * 8, lds + (buf) * 4096 + (s1 & ~63) * 8);                    \
    gload16(sb + s0 * 8, lds + 12288 + (buf) * 4096 + (s0 & ~63) * 8);            \
    gload16(sb + s1 * 8, lds + 12288 + (buf) * 4096 + (s1 & ~63) * 8);            \
  } while (0)

#define RCOMPUTE(j)                                                               \
  do {                                                                            \
    const ushort_t* Ab = lds + (j) * 4096;                                        \
    const ushort_t* Bb = lds + 12288 + (j) * 4096;                                \
    bf16x8 af[4], bw[4];                                                          \
    _Pragma("unroll")                                                             \
    for (int mi = 0; mi < 4; ++mi)                                                \
      af[mi] = *(const bf16x8*)(Ab + (chunk * 128 + wm * 64 + mi * 16 + r15) * 8);\
    _Pragma("unroll")                                                             \
    for (int ni = 0; ni < 4; ++ni)                                                \
      bw[ni] = *(const bf16x8*)(Bb + (chunk * 128 + wn * 64 + ni * 16 + r15) * 8);\
    __builtin_amdgcn_s_setprio(1);                                                \
    _Pragma("unroll")                                                             \
    for (int mi = 0; mi < 4; ++mi)                                                \
      _Pragma("unroll")                                                           \
      for (int ni = 0; ni < 4; ++ni)                                              \
        acc[mi][ni] = __builtin_amdgcn_mfma_f32_16x16x32_bf16(af[mi], bw[ni],     \
                                                              acc[mi][ni], 0, 0, 0); \
    __builtin_amdgcn_s_setprio(0);                                                \
    SCHED();                                                                      \
  } while (0)

  RSTAGE(0, 0); RSTAGE(1, 1);
  VMCNT4();
  SBAR(); SCHED();
  for (int kt0 = 0; kt0 < 30; kt0 += 3) {
    RSTAGE(kt0 + 2, 2); RCOMPUTE(0); VMCNT4(); SBAR(); SCHED();
    RSTAGE(kt0 + 3, 0); RCOMPUTE(1); VMCNT4(); SBAR(); SCHED();
    RSTAGE(kt0 + 4, 1); RCOMPUTE(2); VMCNT4(); SBAR(); SCHED();
  }
  RCOMPUTE(0); VMCNT0(); SBAR(); SCHED();
  RCOMPUTE(1);
#undef RSTAGE
#undef RCOMPUTE
}

// ---------------------------------------------------------------------------
// Kernel 2: Q/K/V projections + fused bias reduce. XCD-swizzled 1D grid 768.
// PACKED outputs: Qhs[bh][qt][chunk8][row64][8], Khs[bh][kt][chunk8][row128][8],
// Vts[bh][kt][chunk16][d64][8].   (verified R15)
// ---------------------------------------------------------------------------
__global__ __launch_bounds__(256, 3) void gemm_qkv_kernel(
    const ushort_t* __restrict__ xb, const ushort_t* __restrict__ kp,
    const ushort_t* __restrict__ vp, const ushort_t* __restrict__ wb,
    const float* __restrict__ alpha, const float* __restrict__ l2part,
    float* __restrict__ biasv,
    ushort_t* __restrict__ Qhs, ushort_t* __restrict__ Khs, ushort_t* __restrict__ Vts) {
  __shared__ ushort_t lds[24576];
  const int fid = blockIdx.x;
  const int xcd = fid & 7, vl = fid >> 3;     // vl in [0,96)
  const int z = vl >> 5, r = vl & 31;
  const int bx = (xcd & 3) * 8 + (r & 7);     // 0..31
  const int by = (xcd >> 2) * 4 + (r >> 3);   // 0..7
  const ushort_t* Ag = z == 0 ? xb : z == 1 ? kp : vp;
  const ushort_t* Wg = wb + (size_t)z * 1048576;
  const int m0 = bx * 128, n0 = by * 128;
  const int t = threadIdx.x;

  // fused bias reduce: the 32 (z==0, by==0) blocks cover all 4096 rows.
  if (z == 0 && by == 0 && t < 128) {
    int row = m0 + t;
    const float* p = l2part + (size_t)row * 32;
    float s = 0.f;
#pragma unroll
    for (int j = 0; j < 8; ++j) {
      float4 v = *(const float4*)(p + j * 4);
      s += (v.x + v.y) + (v.z + v.w);
    }
    biasv[row] = __logf(alpha[row]) - 0.5f * s;
  }

  f32x4 acc[4][4] = {};
  gemm_tile_r3(Ag, Wg, bx, by, acc, lds);
  const int w = t >> 6, lane = t & 63;
  const int wm = w >> 1, wn = w & 1;
  const int hi = lane >> 4, r15 = lane & 15;
  const int b = m0 >> 9, h0 = n0 >> 6;

  __syncthreads();
  if (z < 2) {
    ushort_t* T = lds;                       // [128][136]
#pragma unroll
    for (int mi = 0; mi < 4; ++mi)
#pragma unroll
      for (int ni = 0; ni < 4; ++ni)
#pragma unroll
        for (int q = 0; q < 4; ++q) {
          int row = wm * 64 + mi * 16 + hi * 4 + q;
          int col = wn * 64 + ni * 16 + r15;
          T[row * 136 + col] = f2bf(acc[mi][ni][q]);
        }
    __syncthreads();
    if (z == 0) {
      const int qt0 = (m0 & 511) >> 6;
#pragma unroll
      for (int i = 0; i < 8; ++i) {
        int c = t + 256 * i;
        int row64 = c & 63, qt_l = (c >> 6) & 1, chunk = (c >> 7) & 7, head_l = (c >> 10) & 1;
        bf16x8 v = *(const bf16x8*)(T + (qt_l * 64 + row64) * 136 + head_l * 64 + chunk * 8);
        int bh = b * 16 + h0 + head_l;
        *(bf16x8*)(Qhs + ((size_t)((bh * 8 + qt0 + qt_l) * 8 + chunk) * 64 + row64) * 8) = v;
      }
    } else {
      const int kt = (m0 & 511) >> 7;
#pragma unroll
      for (int i = 0; i < 8; ++i) {
        int c = t + 256 * i;
        int row128 = c & 127, chunk = (c >> 7) & 7, head_l = (c >> 10) & 1;
        bf16x8 v = *(const bf16x8*)(T + row128 * 136 + head_l * 64 + chunk * 8);
        int bh = b * 16 + h0 + head_l;
        *(bf16x8*)(Khs + ((size_t)((bh * 4 + kt) * 8 + chunk) * 128 + row128) * 8) = v;
      }
    }
  } else {
    ushort_t* T = lds;                       // [128][129]
#pragma unroll
    for (int mi = 0; mi < 4; ++mi)
#pragma unroll
      for (int ni = 0; ni < 4; ++ni)
#pragma unroll
        for (int q = 0; q < 4; ++q) {
          int row = wm * 64 + mi * 16 + hi * 4 + q;
          int col = wn * 64 + ni * 16 + r15;
          T[row * 129 + col] = f2bf(acc[mi][ni][q]);
        }
    __syncthreads();
    const int kt = (m0 & 511) >> 7;
#pragma unroll
    for (int i = 0; i < 8; ++i) {
      int c = t + 256 * i;
      int d64 = c & 63, head_l = (c >> 6) & 1, chunkp = (c >> 7) & 15;
      bf16x8 v;
#pragma unroll
      for (int j = 0; j < 8; ++j)
        v[j] = *(const __bf16*)(T + (chunkp * 8 + j) * 129 + head_l * 64 + d64);
      int bh = b * 16 + h0 + head_l;
      *(bf16x8*)(Vts + ((size_t)((bh * 4 + kt) * 16 + chunkp) * 64 + d64) * 8) = v;
    }
  }
}

// ---------------------------------------------------------------------------
// Kernel 3: attention, DIRECT-L2 fragment reads (no K/V/Q LDS staging — per
// guide m169: staging L2-resident data is pure overhead). Packed Qhs/Khs/Vts
// are exactly fragment-ordered, so each lane's 16B global read is the same
// bytes the old LDS read returned. No barriers except one for biasl; per-wave
// Pl transpose ordered by LGKM0+SCHED fences (R13-proven). Swapped QK^T
// (verified R14): lane holds S[key f*16+hi*4+q][qrow r15].
// ---------------------------------------------------------------------------
__global__ __launch_bounds__(256, 2) void attn_kernel(
    const ushort_t* __restrict__ Qhs, const ushort_t* __restrict__ Khs,
    const ushort_t* __restrict__ Vts, const float* __restrict__ biasv,
    float* __restrict__ attn_out, ushort_t* __restrict__ Og) {
  __shared__ ushort_t Pl[8704];     // 4 waves x [16 qrow][136 key] bf16
  __shared__ float biasl[512];
  const int fid = blockIdx.x;
  const int v_ = (fid & 7) * 128 + (fid >> 3);   // bijective over 1024
  const int bh = v_ >> 3, qt = v_ & 7;           // consecutive v_ share bh
  const int b = bh >> 4, h = bh & 15;
  const int t = threadIdx.x, w = t >> 6, lane = t & 63;
  const int hi = lane >> 4, r15 = lane & 15;

  {
    float2 bv2 = *(const float2*)(biasv + b * 512 + t * 2);
    biasl[t * 2] = bv2.x; biasl[t * 2 + 1] = bv2.y;
  }
  __syncthreads();                  // the only block-wide barrier

  // Q fragments: direct 16B reads (Qhs slab is linear fragment order)
  const ushort_t* sq = Qhs + (size_t)(bh * 8 + qt) * 4096;
  bf16x8 aq[2];
#pragma unroll
  for (int ks = 0; ks < 2; ++ks)
    aq[ks] = *(const bf16x8*)(sq + ((ks * 4 + hi) * 64 + w * 16 + r15) * 8);

  // ---- S^T = K Q^T, K fragments direct from L2 ----
  const ushort_t* Kb = Khs + (size_t)bh * 4 * 8192;
  f32x4 acc[32] = {};
#pragma unroll
  for (int kt = 0; kt < 4; ++kt) {
    const ushort_t* sk = Kb + kt * 8192;
    __builtin_amdgcn_s_setprio(1);
#pragma unroll
    for (int mf = 0; mf < 8; ++mf)
#pragma unroll
      for (int ks = 0; ks < 2; ++ks) {
        bf16x8 bk = *(const bf16x8*)(sk + ((ks * 4 + hi) * 128 + mf * 16 + r15) * 8);
        acc[kt * 8 + mf] = __builtin_amdgcn_mfma_f32_16x16x32_bf16(bk, aq[ks], acc[kt * 8 + mf], 0, 0, 0);
      }
    __builtin_amdgcn_s_setprio(0);
  }

  // ---- bias + softmax: one qrow per lane, 128 vals; reduce over hi-group ----
  float mx = -1e30f;
#pragma unroll
  for (int f = 0; f < 32; ++f) {
    f32x4 bv4 = *(const f32x4*)(biasl + f * 16 + hi * 4);
    acc[f] += bv4;
    float m01 = fmaxf(acc[f][0], acc[f][1]);
    float m23 = fmaxf(acc[f][2], acc[f][3]);
    mx = fmaxf(mx, fmaxf(m01, m23));
  }
  mx = fmaxf(mx, __shfl_xor(mx, 16));
  mx = fmaxf(mx, __shfl_xor(mx, 32));
  float sm = 0.f;
#pragma unroll
  for (int f = 0; f < 32; ++f)
#pragma unroll
    for (int q = 0; q < 4; ++q) {
      float p = __expf(acc[f][q] - mx);
      acc[f][q] = p;
      sm += p;
    }
  sm += __shfl_xor(sm, 16);
  sm += __shfl_xor(sm, 32);
  float inv = 1.0f / sm;
#pragma unroll
  for (int f = 0; f < 32; ++f)
#pragma unroll
    for (int q = 0; q < 4; ++q)
      acc[f][q] *= inv;

  // ---- O = P V : Pl per-wave [16 qrow][136 key]; V fragments direct L2 ----
  ushort_t* Plw = Pl + w * 2176;
  const ushort_t* Vb = Vts + (size_t)bh * 4 * 8192;
  f32x4 oacc[4] = {};
#pragma unroll
  for (int kt = 0; kt < 4; ++kt) {
    LGKM0(); SCHED();               // WAR: prior kt's pa reads landed
#pragma unroll
    for (int fl = 0; fl < 8; ++fl) {
      int f = kt * 8 + fl;
      ushort4 o;
      o.x = f2bf(acc[f][0]); o.y = f2bf(acc[f][1]);
      o.z = f2bf(acc[f][2]); o.w = f2bf(acc[f][3]);
      *(ushort4*)(Plw + r15 * 136 + fl * 16 + hi * 4) = o;
    }
    LGKM0(); SCHED();               // RAW: slab visible before cross-lane reads
    const ushort_t* sv = Vb + kt * 8192;
    __builtin_amdgcn_s_setprio(1);
#pragma unroll
    for (int ks = 0; ks < 4; ++ks) {
      bf16x8 pa = *(const bf16x8*)(Plw + r15 * 136 + ks * 32 + hi * 8);
#pragma unroll
      for (int df = 0; df < 4; ++df) {
        bf16x8 vb = *(const bf16x8*)(sv + ((ks * 4 + hi) * 64 + df * 16 + r15) * 8);
        oacc[df] = __builtin_amdgcn_mfma_f32_16x16x32_bf16(pa, vb, oacc[df], 0, 0, 0);
      }
    }
    __builtin_amdgcn_s_setprio(0);
  }

  // ---- attn_out: vectorized f32x4 stores (row = qrow r15, col = f*16+hi*4) ----
  {
    float* ao = attn_out + ((size_t)bh * 512 + qt * 64 + w * 16 + r15) * 512 + hi * 4;
#pragma unroll
    for (int f = 0; f < 32; ++f)
      *(f32x4*)(ao + f * 16) = acc[f];
  }

  // ---- Og (bf16, PACKED for gemm_out; oacc layout unchanged) ----
  {
    const int mtile = b * 4 + (qt >> 1);
    const int rowl = (qt & 1) * 64 + w * 16 + hi * 4;
#pragma unroll
    for (int df = 0; df < 4; ++df) {
      int kto = h * 2 + (df >> 1);
      int chunko = (df & 1) * 2 + (r15 >> 3);
      size_t ob = ((size_t)((mtile * 32 + kto) * 4 + chunko) * 1024 + (r15 & 7));
#pragma unroll
      for (int q = 0; q < 4; ++q)
        Og[ob + (size_t)(rowl + q) * 8] = f2bf(oacc[df][q]);
    }
  }
}

// ---------------------------------------------------------------------------
// Kernel 4: out = O @ wp^T + b_p. XCD-swizzled; LDS float4 epilogue.
// (verified R12/R15)
// ---------------------------------------------------------------------------
__global__ __launch_bounds__(256, 3) void gemm_out_kernel(
    const ushort_t* __restrict__ Og, const ushort_t* __restrict__ wb,
    const float* __restrict__ bp, float* __restrict__ out) {
  __shared__ ushort_t lds[24576];
  const int fid = blockIdx.x;
  const int xcd = fid & 7, r = fid >> 3;      // r in [0,32)
  const int bx = (xcd & 3) * 8 + (r & 7);     // 0..31
  const int by = (xcd >> 2) * 4 + (r >> 3);   // 0..7
  const int m0 = bx * 128, n0 = by * 128;
  f32x4 acc[4][4] = {};
  gemm_tile_r3(Og, wb + 3 * 1048576, bx, by, acc, lds);
  const int t = threadIdx.x, w = t >> 6, lane = t & 63;
  const int wm = w >> 1, wn = w & 1;
  const int hi = lane >> 4, r15 = lane & 15;
  float* T2 = (float*)lds;                   // [64][128] fp32 = 32KB per half
#pragma unroll
  for (int hh = 0; hh < 2; ++hh) {
    __syncthreads();                         // prior phase's LDS reads done
    if (wm == hh) {
#pragma unroll
      for (int mi = 0; mi < 4; ++mi)
#pragma unroll
        for (int ni = 0; ni < 4; ++ni)
#pragma unroll
          for (int q = 0; q < 4; ++q) {
            int row = mi * 16 + hi * 4 + q;  // 0..63 within half
            int col = wn * 64 + ni * 16 + r15;
            T2[row * 128 + col] = acc[mi][ni][q];
          }
    }
    __syncthreads();
#pragma unroll
    for (int i = 0; i < 8; ++i) {
      int c = t + 256 * i;
      int row = c >> 5, col0 = (c & 31) * 4;
      float4 v = *(const float4*)(T2 + row * 128 + col0);
      float4 bb = *(const float4*)(bp + n0 + col0);
      v.x += bb.x; v.y += bb.y; v.z += bb.z; v.w += bb.w;
      *(float4*)(out + (size_t)(m0 + hh * 64 + row) * 1024 + n0 + col0) = v;
    }
  }
}

// ---------------------------------------------------------------------------
// Launch. Workspace:
//   0 xb | 8MB kp | 16MB vp | 24MB Qhs | 32MB Khs | 40MB Vts | 48MB wb
//   56MB biasv (16KB) | 57MB l2part (512KB).  Og reuses xb.
// ---------------------------------------------------------------------------
extern "C" void kernel_launch(void* const* d_in, const int* in_sizes, int n_in,
                              void* d_out, int out_size, void* d_ws, size_t ws_size,
                              hipStream_t stream) {
  const float* x      = (const float*)d_in[0];
  const float* mu     = (const float*)d_in[1];
  const float* logvar = (const float*)d_in[2];
  const float* alpha  = (const float*)d_in[3];
  const float* wq = (const float*)d_in[6];
  const float* wk = (const float*)d_in[7];
  const float* wv = (const float*)d_in[8];
  const float* wp = (const float*)d_in[9];
  const float* bp = (const float*)d_in[10];

  float* out      = (float*)d_out;
  float* attn_out = out + (size_t)M_ * C_;

  char* ws = (char*)d_ws;
  ushort_t* xb     = (ushort_t*)(ws);
  ushort_t* kp     = (ushort_t*)(ws + (size_t)8  * 1048576);
  ushort_t* vp     = (ushort_t*)(ws + (size_t)16 * 1048576);
  ushort_t* Qhs    = (ushort_t*)(ws + (size_t)24 * 1048576);
  ushort_t* Khs    = (ushort_t*)(ws + (size_t)32 * 1048576);
  ushort_t* Vts    = (ushort_t*)(ws + (size_t)40 * 1048576);
  ushort_t* wb     = (ushort_t*)(ws + (size_t)48 * 1048576);
  float*    biasv  = (float*)   (ws + (size_t)56 * 1048576);
  float*    l2part = (float*)   (ws + (size_t)57 * 1048576);
  ushort_t* Og     = xb;

  prep_pack_kernel<<<2048, 256, 0, stream>>>(x, mu, logvar, wq, wk, wv, wp,
                                             xb, kp, vp, wb, l2part);
  gemm_qkv_kernel<<<768, 256, 0, stream>>>(xb, kp, vp, wb,
                                           alpha, l2part, biasv,
                                           Qhs, Khs, Vts);
  attn_kernel<<<1024, 256, 0, stream>>>(Qhs, Khs, Vts, biasv, attn_out, Og);
  gemm_out_kernel<<<256, 256, 0, stream>>>(Og, wb, bp, out);
}

// Round 17
// 110.088 us; speedup vs baseline: 1.1481x; 1.1481x over previous
//
#include <hip/hip_runtime.h>
#include <hip/hip_bf16.h>

// Problem constants
#define B_  8
#define N_  512
#define C_  1024
#define H_  16
#define HD_ 64
#define M_  4096   // B*N

typedef float  f32x4  __attribute__((ext_vector_type(4)));
typedef __bf16 bf16x8 __attribute__((ext_vector_type(8)));
typedef unsigned short ushort_t;

__device__ __forceinline__ ushort_t f2bf(float f) {
  union { float f; unsigned int u; } un; un.f = f;
  unsigned int u = un.u;
  return (ushort_t)((u + 0x7fffu + ((u >> 16) & 1u)) >> 16);  // RNE
}

// async global->LDS, 16B per lane; lds pointer must be wave-uniform (lane*16 added by HW)
__device__ __forceinline__ void gload16(const void* g, void* l) {
  __builtin_amdgcn_global_load_lds((const __attribute__((address_space(1))) void*)g,
                                   (__attribute__((address_space(3))) void*)l, 16, 0, 0);
}
#define SBAR()  __builtin_amdgcn_s_barrier()
#define SCHED() __builtin_amdgcn_sched_barrier(0)
#define VMCNT4() asm volatile("s_waitcnt vmcnt(4)" ::: "memory")
#define VMCNT0() asm volatile("s_waitcnt vmcnt(0)" ::: "memory")

// Packed GEMM-operand layout (verified R8/R9):
//   PACK(row,k) = (((row>>7)*32 + (k>>5))*4 + ((k>>3)&3))*1024 + (row&127)*8 + (k&7)
// [mtile][kt][chunk4][row128][8] — the exact linear order gemm staging consumes.

// ---------------------------------------------------------------------------
// Kernel 1: tile-packed prep. Block = one [128r x 32k] tile. (verified R9)
// ---------------------------------------------------------------------------
__global__ __launch_bounds__(256) void prep_pack_kernel(
    const float* __restrict__ x, const float* __restrict__ mu,
    const float* __restrict__ logvar,
    const float* __restrict__ wq, const float* __restrict__ wk,
    const float* __restrict__ wv, const float* __restrict__ wp,
    ushort_t* __restrict__ xb, ushort_t* __restrict__ kp, ushort_t* __restrict__ vp,
    ushort_t* __restrict__ wb, float* __restrict__ l2part) {
  const int bid = blockIdx.x, t = threadIdx.x;
  const int row = t >> 1, cg = (t & 1) * 16;   // row 0..127, k-group 0 or 16
  const int c0 = cg >> 3;                      // chunk base: 0 or 2

  if (bid < 1024) {
    const int mt = bid >> 5, kt = bid & 31;
    const size_t src = (size_t)(mt * 128 + row) * 1024 + kt * 32 + cg;
    ushort_t tx[16] __attribute__((aligned(16)));
    ushort_t tk[16] __attribute__((aligned(16)));
    ushort_t tv[16] __attribute__((aligned(16)));
    float l2 = 0.f;
#pragma unroll
    for (int j = 0; j < 4; ++j) {
      float4 xv = *(const float4*)(x + src + j * 4);
      float4 mv = *(const float4*)(mu + src + j * 4);
      float4 lv = *(const float4*)(logvar + src + j * 4);
      float xa[4] = {xv.x, xv.y, xv.z, xv.w};
      float ma[4] = {mv.x, mv.y, mv.z, mv.w};
      float la[4] = {lv.x, lv.y, lv.z, lv.w};
#pragma unroll
      for (int i = 0; i < 4; ++i) {
        int e = j * 4 + i;
        float bv  = __expf(la[i]) + 8.0f;   // exp(logvar) + sqrt(HD)
        float inv = 1.0f / bv;
        float kf  = ma[i] * inv;
        l2 += ma[i] * kf;                   // mu^2 / bv
        tx[e] = f2bf(xa[i]); tk[e] = f2bf(kf); tv[e] = f2bf(8.0f * kf);
      }
    }
    const size_t tb = (size_t)((mt * 32 + kt) * 4) * 1024 + row * 8;
    *(bf16x8*)(xb + tb + c0 * 1024)       = *(const bf16x8*)(tx);
    *(bf16x8*)(xb + tb + (c0 + 1) * 1024) = *(const bf16x8*)(tx + 8);
    *(bf16x8*)(kp + tb + c0 * 1024)       = *(const bf16x8*)(tk);
    *(bf16x8*)(kp + tb + (c0 + 1) * 1024) = *(const bf16x8*)(tk + 8);
    *(bf16x8*)(vp + tb + c0 * 1024)       = *(const bf16x8*)(tv);
    *(bf16x8*)(vp + tb + (c0 + 1) * 1024) = *(const bf16x8*)(tv + 8);
    l2 += __shfl_xor(l2, 1);               // pair holds full 32-k partial
    if ((t & 1) == 0) l2part[(size_t)(mt * 128 + row) * 32 + kt] = l2;
  } else {
    const int idx = bid - 1024;
    const int sel = idx >> 8, nt = (idx >> 5) & 7, kt = idx & 31;
    const float* src = sel == 0 ? wq : sel == 1 ? wk : sel == 2 ? wv : wp;
    const size_t so = (size_t)(nt * 128 + row) * 1024 + kt * 32 + cg;
    ushort_t tw[16] __attribute__((aligned(16)));
#pragma unroll
    for (int j = 0; j < 4; ++j) {
      float4 v = *(const float4*)(src + so + j * 4);
      tw[j * 4 + 0] = f2bf(v.x); tw[j * 4 + 1] = f2bf(v.y);
      tw[j * 4 + 2] = f2bf(v.z); tw[j * 4 + 3] = f2bf(v.w);
    }
    ushort_t* dst = wb + (size_t)sel * 1048576;
    const size_t tb = (size_t)((nt * 32 + kt) * 4) * 1024 + row * 8;
    *(bf16x8*)(dst + tb + c0 * 1024)       = *(const bf16x8*)(tw);
    *(bf16x8*)(dst + tb + (c0 + 1) * 1024) = *(const bf16x8*)(tw + 8);
  }
}

// ---------------------------------------------------------------------------
// GEMM core, 128x128 tile, BK=32, 256 thr, RING-3 LDS (48KB, 3 blocks/CU).
// PACKED operands: staging is 2 fully-contiguous 8KB runs per tile.
// ---------------------------------------------------------------------------
__device__ __forceinline__ void gemm_tile_r3(const ushort_t* __restrict__ Ag,
                                             const ushort_t* __restrict__ Wg,
                                             int amt, int ant, f32x4 acc[4][4],
                                             ushort_t* lds) {
  const int t = threadIdx.x;
  const int w = t >> 6, lane = t & 63;
  const int wm = w >> 1, wn = w & 1;
  const int chunk = lane >> 4, r15 = lane & 15;
  const int s0 = t, s1 = t + 256;

#define RSTAGE(kt, buf)                                                           \
  do {                                                                            \
    const ushort_t* sa = Ag + (size_t)(amt * 32 + (kt)) * 4096;                   \
    const ushort_t* sb = Wg + (size_t)(ant * 32 + (kt)) * 4096;                   \
    gload16(sa + s0 * 8, lds + (buf) * 4096 + (s0 & ~63) * 8);                    \
    gload16(sa + s1 * 8, lds + (buf) * 4096 + (s1 & ~63) * 8);                    \
    gload16(sb + s0 * 8, lds + 12288 + (buf) * 4096 + (s0 & ~63) * 8);            \
    gload16(sb + s1 * 8, lds + 12288 + (buf) * 4096 + (s1 & ~63) * 8);            \
  } while (0)

#define RCOMPUTE(j)                                                               \
  do {                                                                            \
    const ushort_t* Ab = lds + (j) * 4096;                                        \
    const ushort_t* Bb = lds + 12288 + (j) * 4096;                                \
    bf16x8 af[4], bw[4];                                                          \
    _Pragma("unroll")                                                             \
    for (int mi = 0; mi < 4; ++mi)                                                \
      af[mi] = *(const bf16x8*)(Ab + (chunk * 128 + wm * 64 + mi * 16 + r15) * 8);\
    _Pragma("unroll")                                                             \
    for (int ni = 0; ni < 4; ++ni)                                                \
      bw[ni] = *(const bf16x8*)(Bb + (chunk * 128 + wn * 64 + ni * 16 + r15) * 8);\
    __builtin_amdgcn_s_setprio(1);                                                \
    _Pragma("unroll")                                                             \
    for (int mi = 0; mi < 4; ++mi)                                                \
      _Pragma("unroll")                                                           \
      for (int ni = 0; ni < 4; ++ni)                                              \
        acc[mi][ni] = __builtin_amdgcn_mfma_f32_16x16x32_bf16(af[mi], bw[ni],     \
                                                              acc[mi][ni], 0, 0, 0); \
    __builtin_amdgcn_s_setprio(0);                                                \
    SCHED();                                                                      \
  } while (0)

  RSTAGE(0, 0); RSTAGE(1, 1);
  VMCNT4();
  SBAR(); SCHED();
  for (int kt0 = 0; kt0 < 30; kt0 += 3) {
    RSTAGE(kt0 + 2, 2); RCOMPUTE(0); VMCNT4(); SBAR(); SCHED();
    RSTAGE(kt0 + 3, 0); RCOMPUTE(1); VMCNT4(); SBAR(); SCHED();
    RSTAGE(kt0 + 4, 1); RCOMPUTE(2); VMCNT4(); SBAR(); SCHED();
  }
  RCOMPUTE(0); VMCNT0(); SBAR(); SCHED();
  RCOMPUTE(1);
#undef RSTAGE
#undef RCOMPUTE
}

// ---------------------------------------------------------------------------
// Kernel 2: Q/K/V projections + fused bias reduce. XCD-swizzled 1D grid 768.
// PACKED outputs: Qhs[bh][qt][chunk8][row64][8], Khs[bh][kt][chunk8][row128][8],
// Vts[bh][kt][chunk16][d64][8].   (verified R15)
// ---------------------------------------------------------------------------
__global__ __launch_bounds__(256, 3) void gemm_qkv_kernel(
    const ushort_t* __restrict__ xb, const ushort_t* __restrict__ kp,
    const ushort_t* __restrict__ vp, const ushort_t* __restrict__ wb,
    const float* __restrict__ alpha, const float* __restrict__ l2part,
    float* __restrict__ biasv,
    ushort_t* __restrict__ Qhs, ushort_t* __restrict__ Khs, ushort_t* __restrict__ Vts) {
  __shared__ ushort_t lds[24576];
  const int fid = blockIdx.x;
  const int xcd = fid & 7, vl = fid >> 3;     // vl in [0,96)
  const int z = vl >> 5, r = vl & 31;
  const int bx = (xcd & 3) * 8 + (r & 7);     // 0..31
  const int by = (xcd >> 2) * 4 + (r >> 3);   // 0..7
  const ushort_t* Ag = z == 0 ? xb : z == 1 ? kp : vp;
  const ushort_t* Wg = wb + (size_t)z * 1048576;
  const int m0 = bx * 128, n0 = by * 128;
  const int t = threadIdx.x;

  // fused bias reduce: the 32 (z==0, by==0) blocks cover all 4096 rows.
  if (z == 0 && by == 0 && t < 128) {
    int row = m0 + t;
    const float* p = l2part + (size_t)row * 32;
    float s = 0.f;
#pragma unroll
    for (int j = 0; j < 8; ++j) {
      float4 v = *(const float4*)(p + j * 4);
      s += (v.x + v.y) + (v.z + v.w);
    }
    biasv[row] = __logf(alpha[row]) - 0.5f * s;
  }

  f32x4 acc[4][4] = {};
  gemm_tile_r3(Ag, Wg, bx, by, acc, lds);
  const int w = t >> 6, lane = t & 63;
  const int wm = w >> 1, wn = w & 1;
  const int hi = lane >> 4, r15 = lane & 15;
  const int b = m0 >> 9, h0 = n0 >> 6;

  __syncthreads();
  if (z < 2) {
    ushort_t* T = lds;                       // [128][136]
#pragma unroll
    for (int mi = 0; mi < 4; ++mi)
#pragma unroll
      for (int ni = 0; ni < 4; ++ni)
#pragma unroll
        for (int q = 0; q < 4; ++q) {
          int row = wm * 64 + mi * 16 + hi * 4 + q;
          int col = wn * 64 + ni * 16 + r15;
          T[row * 136 + col] = f2bf(acc[mi][ni][q]);
        }
    __syncthreads();
    if (z == 0) {
      const int qt0 = (m0 & 511) >> 6;
#pragma unroll
      for (int i = 0; i < 8; ++i) {
        int c = t + 256 * i;
        int row64 = c & 63, qt_l = (c >> 6) & 1, chunk = (c >> 7) & 7, head_l = (c >> 10) & 1;
        bf16x8 v = *(const bf16x8*)(T + (qt_l * 64 + row64) * 136 + head_l * 64 + chunk * 8);
        int bh = b * 16 + h0 + head_l;
        *(bf16x8*)(Qhs + ((size_t)((bh * 8 + qt0 + qt_l) * 8 + chunk) * 64 + row64) * 8) = v;
      }
    } else {
      const int kt = (m0 & 511) >> 7;
#pragma unroll
      for (int i = 0; i < 8; ++i) {
        int c = t + 256 * i;
        int row128 = c & 127, chunk = (c >> 7) & 7, head_l = (c >> 10) & 1;
        bf16x8 v = *(const bf16x8*)(T + row128 * 136 + head_l * 64 + chunk * 8);
        int bh = b * 16 + h0 + head_l;
        *(bf16x8*)(Khs + ((size_t)((bh * 4 + kt) * 8 + chunk) * 128 + row128) * 8) = v;
      }
    }
  } else {
    ushort_t* T = lds;                       // [128][129]
#pragma unroll
    for (int mi = 0; mi < 4; ++mi)
#pragma unroll
      for (int ni = 0; ni < 4; ++ni)
#pragma unroll
        for (int q = 0; q < 4; ++q) {
          int row = wm * 64 + mi * 16 + hi * 4 + q;
          int col = wn * 64 + ni * 16 + r15;
          T[row * 129 + col] = f2bf(acc[mi][ni][q]);
        }
    __syncthreads();
    const int kt = (m0 & 511) >> 7;
#pragma unroll
    for (int i = 0; i < 8; ++i) {
      int c = t + 256 * i;
      int d64 = c & 63, head_l = (c >> 6) & 1, chunkp = (c >> 7) & 15;
      bf16x8 v;
#pragma unroll
      for (int j = 0; j < 8; ++j)
        v[j] = *(const __bf16*)(T + (chunkp * 8 + j) * 129 + head_l * 64 + d64);
      int bh = b * 16 + h0 + head_l;
      *(bf16x8*)(Vts + ((size_t)((bh * 4 + kt) * 16 + chunkp) * 64 + d64) * 8) = v;
    }
  }
}

// ---------------------------------------------------------------------------
// Kernel 3: attention (swapped QK^T + LDS staging RESTORED — R16 proved the
// staging is load-bearing: direct-L2 fragment reads cost +15.8us). XCD
// swizzle on 1D grid 1024. (attn body verified R14/R15)
// ---------------------------------------------------------------------------
__global__ __launch_bounds__(256, 2) void attn_kernel(
    const ushort_t* __restrict__ Qhs, const ushort_t* __restrict__ Khs,
    const ushort_t* __restrict__ Vts, const float* __restrict__ biasv,
    float* __restrict__ attn_out, ushort_t* __restrict__ Og) {
  __shared__ ushort_t Qt[4096];
  __shared__ ushort_t KV[16384];
  __shared__ ushort_t Pl[8704];     // 4 waves x [16 qrow][136 key] bf16
  __shared__ float biasl[512];
  const int fid = blockIdx.x;
  const int v_ = (fid & 7) * 128 + (fid >> 3);   // bijective over 1024
  const int bh = v_ >> 3, qt = v_ & 7;           // consecutive v_ share bh
  const int b = bh >> 4, h = bh & 15;
  const int t = threadIdx.x, w = t >> 6, lane = t & 63;
  const int hi = lane >> 4, r15 = lane & 15;

  {
    float2 bv2 = *(const float2*)(biasv + b * 512 + t * 2);
    biasl[t * 2] = bv2.x; biasl[t * 2 + 1] = bv2.y;
  }
  {
    const ushort_t* sq = Qhs + (size_t)(bh * 8 + qt) * 4096;
    gload16(sq + t * 8, Qt + (t & ~63) * 8);
    gload16(sq + (t + 256) * 8, Qt + ((t + 256) & ~63) * 8);
  }

#define STAGE_K(kt, buf)                                                               \
  do {                                                                                 \
    const ushort_t* sk = Khs + (size_t)(bh * 4 + (kt)) * 8192;                         \
    _Pragma("unroll")                                                                  \
    for (int r = 0; r < 4; ++r) {                                                      \
      int s = r * 256 + t;                                                             \
      gload16(sk + s * 8, KV + (buf) * 8192 + (s & ~63) * 8);                          \
    }                                                                                  \
  } while (0)
#define STAGE_V(kt, buf)                                                               \
  do {                                                                                 \
    const ushort_t* sv = Vts + (size_t)(bh * 4 + (kt)) * 8192;                         \
    _Pragma("unroll")                                                                  \
    for (int r = 0; r < 4; ++r) {                                                      \
      int s = r * 256 + t;                                                             \
      gload16(sv + s * 8, KV + (buf) * 8192 + (s & ~63) * 8);                          \
    }                                                                                  \
  } while (0)

  STAGE_K(0, 0);
  f32x4 acc[32] = {};
  bf16x8 aq[2];
  int cur = 0;

  // ---- S^T = K Q^T : acc[f][q] = S[key f*16+hi*4+q][qrow r15] ----
#pragma unroll
  for (int kt = 0; kt < 4; ++kt) {
    if (kt < 3) STAGE_K(kt + 1, cur ^ 1);
    else        STAGE_V(0, cur ^ 1);
    VMCNT4();
    SBAR();
    SCHED();
    if (kt == 0) {
#pragma unroll
      for (int ks = 0; ks < 2; ++ks)
        aq[ks] = *(const bf16x8*)(Qt + ((ks * 4 + hi) * 64 + w * 16 + r15) * 8);
    }
    __builtin_amdgcn_s_setprio(1);
#pragma unroll
    for (int mf = 0; mf < 8; ++mf)
#pragma unroll
      for (int ks = 0; ks < 2; ++ks) {
        bf16x8 bk = *(const bf16x8*)(KV + cur * 8192 + ((ks * 4 + hi) * 128 + mf * 16 + r15) * 8);
        acc[kt * 8 + mf] = __builtin_amdgcn_mfma_f32_16x16x32_bf16(bk, aq[ks], acc[kt * 8 + mf], 0, 0, 0);
      }
    __builtin_amdgcn_s_setprio(0);
    SCHED();
    SBAR();
    SCHED();
    cur ^= 1;
  }

  // ---- bias + softmax: one qrow per lane, 128 vals; reduce over hi-group ----
  float mx = -1e30f;
#pragma unroll
  for (int f = 0; f < 32; ++f) {
    f32x4 bv4 = *(const f32x4*)(biasl + f * 16 + hi * 4);
    acc[f] += bv4;
    float m01 = fmaxf(acc[f][0], acc[f][1]);
    float m23 = fmaxf(acc[f][2], acc[f][3]);
    mx = fmaxf(mx, fmaxf(m01, m23));
  }
  mx = fmaxf(mx, __shfl_xor(mx, 16));
  mx = fmaxf(mx, __shfl_xor(mx, 32));
  float sm = 0.f;
#pragma unroll
  for (int f = 0; f < 32; ++f)
#pragma unroll
    for (int q = 0; q < 4; ++q) {
      float p = __expf(acc[f][q] - mx);
      acc[f][q] = p;
      sm += p;
    }
  sm += __shfl_xor(sm, 16);
  sm += __shfl_xor(sm, 32);
  float inv = 1.0f / sm;
#pragma unroll
  for (int f = 0; f < 32; ++f)
#pragma unroll
    for (int q = 0; q < 4; ++q)
      acc[f][q] *= inv;

  // ---- O = P V (Pl: per-wave [16 qrow][136 key]; A-frag = P[r15][k] ) ----
  ushort_t* Plw = Pl + w * 2176;
  f32x4 oacc[4] = {};
#pragma unroll
  for (int kt = 0; kt < 4; ++kt) {
    if (kt < 3) STAGE_V(kt + 1, cur ^ 1);
#pragma unroll
    for (int fl = 0; fl < 8; ++fl) {
      int f = kt * 8 + fl;
      ushort4 o;
      o.x = f2bf(acc[f][0]); o.y = f2bf(acc[f][1]);
      o.z = f2bf(acc[f][2]); o.w = f2bf(acc[f][3]);
      *(ushort4*)(Plw + r15 * 136 + fl * 16 + hi * 4) = o;
    }
    if (kt < 3) VMCNT4(); else VMCNT0();
    SBAR();
    SCHED();
    __builtin_amdgcn_s_setprio(1);
#pragma unroll
    for (int ks = 0; ks < 4; ++ks) {
      bf16x8 pa = *(const bf16x8*)(Plw + r15 * 136 + ks * 32 + hi * 8);
#pragma unroll
      for (int df = 0; df < 4; ++df) {
        bf16x8 vb = *(const bf16x8*)(KV + cur * 8192 + ((ks * 4 + hi) * 64 + df * 16 + r15) * 8);
        oacc[df] = __builtin_amdgcn_mfma_f32_16x16x32_bf16(pa, vb, oacc[df], 0, 0, 0);
      }
    }
    __builtin_amdgcn_s_setprio(0);
    SCHED();
    SBAR();
    SCHED();
    cur ^= 1;
  }

  // ---- attn_out: vectorized f32x4 stores (row = qrow r15, col = f*16+hi*4) ----
  {
    float* ao = attn_out + ((size_t)bh * 512 + qt * 64 + w * 16 + r15) * 512 + hi * 4;
#pragma unroll
    for (int f = 0; f < 32; ++f)
      *(f32x4*)(ao + f * 16) = acc[f];
  }

  // ---- Og (bf16, PACKED for gemm_out; oacc layout unchanged) ----
  {
    const int mtile = b * 4 + (qt >> 1);
    const int rowl = (qt & 1) * 64 + w * 16 + hi * 4;
#pragma unroll
    for (int df = 0; df < 4; ++df) {
      int kto = h * 2 + (df >> 1);
      int chunko = (df & 1) * 2 + (r15 >> 3);
      size_t ob = ((size_t)((mtile * 32 + kto) * 4 + chunko) * 1024 + (r15 & 7));
#pragma unroll
      for (int q = 0; q < 4; ++q)
        Og[ob + (size_t)(rowl + q) * 8] = f2bf(oacc[df][q]);
    }
  }
#undef STAGE_K
#undef STAGE_V
}

// ---------------------------------------------------------------------------
// Kernel 4: out = O @ wp^T + b_p. XCD-swizzled; LDS float4 epilogue.
// (verified R12/R15)
// ---------------------------------------------------------------------------
__global__ __launch_bounds__(256, 3) void gemm_out_kernel(
    const ushort_t* __restrict__ Og, const ushort_t* __restrict__ wb,
    const float* __restrict__ bp, float* __restrict__ out) {
  __shared__ ushort_t lds[24576];
  const int fid = blockIdx.x;
  const int xcd = fid & 7, r = fid >> 3;      // r in [0,32)
  const int bx = (xcd & 3) * 8 + (r & 7);     // 0..31
  const int by = (xcd >> 2) * 4 + (r >> 3);   // 0..7
  const int m0 = bx * 128, n0 = by * 128;
  f32x4 acc[4][4] = {};
  gemm_tile_r3(Og, wb + 3 * 1048576, bx, by, acc, lds);
  const int t = threadIdx.x, w = t >> 6, lane = t & 63;
  const int wm = w >> 1, wn = w & 1;
  const int hi = lane >> 4, r15 = lane & 15;
  float* T2 = (float*)lds;                   // [64][128] fp32 = 32KB per half
#pragma unroll
  for (int hh = 0; hh < 2; ++hh) {
    __syncthreads();                         // prior phase's LDS reads done
    if (wm == hh) {
#pragma unroll
      for (int mi = 0; mi < 4; ++mi)
#pragma unroll
        for (int ni = 0; ni < 4; ++ni)
#pragma unroll
          for (int q = 0; q < 4; ++q) {
            int row = mi * 16 + hi * 4 + q;  // 0..63 within half
            int col = wn * 64 + ni * 16 + r15;
            T2[row * 128 + col] = acc[mi][ni][q];
          }
    }
    __syncthreads();
#pragma unroll
    for (int i = 0; i < 8; ++i) {
      int c = t + 256 * i;
      int row = c >> 5, col0 = (c & 31) * 4;
      float4 v = *(const float4*)(T2 + row * 128 + col0);
      float4 bb = *(const float4*)(bp + n0 + col0);
      v.x += bb.x; v.y += bb.y; v.z += bb.z; v.w += bb.w;
      *(float4*)(out + (size_t)(m0 + hh * 64 + row) * 1024 + n0 + col0) = v;
    }
  }
}

// ---------------------------------------------------------------------------
// Launch. Workspace:
//   0 xb | 8MB kp | 16MB vp | 24MB Qhs | 32MB Khs | 40MB Vts | 48MB wb
//   56MB biasv (16KB) | 57MB l2part (512KB).  Og reuses xb.
// ---------------------------------------------------------------------------
extern "C" void kernel_launch(void* const* d_in, const int* in_sizes, int n_in,
                              void* d_out, int out_size, void* d_ws, size_t ws_size,
                              hipStream_t stream) {
  const float* x      = (const float*)d_in[0];
  const float* mu     = (const float*)d_in[1];
  const float* logvar = (const float*)d_in[2];
  const float* alpha  = (const float*)d_in[3];
  const float* wq = (const float*)d_in[6];
  const float* wk = (const float*)d_in[7];
  const float* wv = (const float*)d_in[8];
  const float* wp = (const float*)d_in[9];
  const float* bp = (const float*)d_in[10];

  float* out      = (float*)d_out;
  float* attn_out = out + (size_t)M_ * C_;

  char* ws = (char*)d_ws;
  ushort_t* xb     = (ushort_t*)(ws);
  ushort_t* kp     = (ushort_t*)(ws + (size_t)8  * 1048576);
  ushort_t* vp     = (ushort_t*)(ws + (size_t)16 * 1048576);
  ushort_t* Qhs    = (ushort_t*)(ws + (size_t)24 * 1048576);
  ushort_t* Khs    = (ushort_t*)(ws + (size_t)32 * 1048576);
  ushort_t* Vts    = (ushort_t*)(ws + (size_t)40 * 1048576);
  ushort_t* wb     = (ushort_t*)(ws + (size_t)48 * 1048576);
  float*    biasv  = (float*)   (ws + (size_t)56 * 1048576);
  float*    l2part = (float*)   (ws + (size_t)57 * 1048576);
  ushort_t* Og     = xb;

  prep_pack_kernel<<<2048, 256, 0, stream>>>(x, mu, logvar, wq, wk, wv, wp,
                                             xb, kp, vp, wb, l2part);
  gemm_qkv_kernel<<<768, 256, 0, stream>>>(xb, kp, vp, wb,
                                           alpha, l2part, biasv,
                                           Qhs, Khs, Vts);
  attn_kernel<<<1024, 256, 0, stream>>>(Qhs, Khs, Vts, biasv, attn_out, Og);
  gemm_out_kernel<<<256, 256, 0, stream>>>(Og, wb, bp, out);
}